// Round 13
// baseline (142.039 us; speedup 1.0000x reference)
//
#include <hip/hip_runtime.h>
#include <math.h>

#define NODES   131072
#define EDGES   1048576
#define FDIM    32
#define HDIM    128
#define NGRAPH  512

#define NB      256         // coarse buckets
#define BSH     9           // tgt>>9 -> bucket; 512 nodes per bucket
#define MAXPER  5120        // slots per bucket
#define EPB     4096        // edges per partition block

typedef __attribute__((ext_vector_type(8))) short short8v;
typedef __attribute__((ext_vector_type(4))) float float4v;
typedef __attribute__((ext_vector_type(2))) float float2v;

__device__ __forceinline__ unsigned short f2bf(float f) {
    union { float f; unsigned int u; } v; v.f = f;
    unsigned int u = v.u;
    unsigned int r = (u + 0x7fffu + ((u >> 16) & 1u)) >> 16;   // RNE
    return (unsigned short)r;
}

// decode 8 fp8 (positions m*8..m*8+7) -> true cols c*16+m for c=0..7
__device__ __forceinline__ void dec8(uint2 r, float* o) {
    float2v a = __builtin_amdgcn_cvt_pk_f32_fp8((int)r.x, false);
    float2v b = __builtin_amdgcn_cvt_pk_f32_fp8((int)r.x, true);
    float2v c = __builtin_amdgcn_cvt_pk_f32_fp8((int)r.y, false);
    float2v d = __builtin_amdgcn_cvt_pk_f32_fp8((int)r.y, true);
    o[0] = a.x; o[1] = a.y; o[2] = b.x; o[3] = b.y;
    o[4] = c.x; o[5] = c.y; o[6] = d.x; o[7] = d.y;
}

// ---------------------------------------------------------------- k1_fused: [0,NB) edge partition | [NB,NB+1024) MFMA projection
__global__ __launch_bounds__(256) void k1_fused(const float* __restrict__ x,
                                                const unsigned short* __restrict__ winfrag,
                                                unsigned char* __restrict__ h0f8,
                                                const int* __restrict__ ei,
                                                const float* __restrict__ ew,
                                                int* __restrict__ coarse_cursor,
                                                uint2* __restrict__ scratch) {
    __shared__ __align__(16) uint2 recL[EPB];     // 32KB
    __shared__ unsigned char bidL[EPB];           // 4KB
    __shared__ int hist[NB];
    __shared__ int excl[NB];
    __shared__ int gb[NB];

    int b = blockIdx.x, t = threadIdx.x;

    if (b < NB) {
        int e0 = b * EPB;
        hist[t] = 0;
        __syncthreads();

        unsigned int rx[16], rw[16];
        int bb[16], lr[16];
#pragma unroll
        for (int i = 0; i < 16; ++i) {
            int e = e0 + t + 256 * i;
            int src = ei[e];
            int tgt = ei[EDGES + e];
            float w = ew[e];
            int bk = tgt >> BSH;
            rx[i] = (unsigned int)src | ((unsigned int)(tgt & ((1 << BSH) - 1)) << 17);
            rw[i] = __float_as_uint(w);
            bb[i] = bk;
            lr[i] = atomicAdd(&hist[bk], 1);
        }
        __syncthreads();

        int hv = hist[t];
        excl[t] = hv;
        __syncthreads();
        for (int off = 1; off < 256; off <<= 1) {
            int v = (t >= off) ? excl[t - off] : 0;
            __syncthreads();
            excl[t] += v;
            __syncthreads();
        }
        int ex = excl[t] - hv;
        gb[t] = atomicAdd(&coarse_cursor[t], hv);
        __syncthreads();
        excl[t] = ex;
        __syncthreads();

#pragma unroll
        for (int i = 0; i < 16; ++i) {
            int pos = excl[bb[i]] + lr[i];
            recL[pos] = make_uint2(rx[i], rw[i]);
            bidL[pos] = (unsigned char)bb[i];
        }
        __syncthreads();

#pragma unroll
        for (int i = 0; i < 16; ++i) {
            int p2 = t + 256 * i;
            int bk = bidL[p2];
            int dst = bk * MAXPER + gb[bk] + (p2 - excl[bk]);
            scratch[dst] = recL[p2];
        }
    } else {
        int mb = b - NB;
        int wid = t >> 6, l = t & 63;
        int base = mb * 128;

        const short8v* wf8 = (const short8v*)winfrag;
        short8v wfr[8];
#pragma unroll
        for (int c = 0; c < 8; ++c) wfr[c] = wf8[c * 64 + l];

#pragma unroll
        for (int s = 0; s < 2; ++s) {
            int strip = base + wid * 32 + s * 16;
            int row = strip + (l & 15);
            const float* xr = x + (size_t)row * FDIM + (l >> 4) * 8;
            float4 x0 = ((const float4*)xr)[0];
            float4 x1 = ((const float4*)xr)[1];
            short8v af;
            af[0] = (short)f2bf(x0.x); af[1] = (short)f2bf(x0.y);
            af[2] = (short)f2bf(x0.z); af[3] = (short)f2bf(x0.w);
            af[4] = (short)f2bf(x1.x); af[5] = (short)f2bf(x1.y);
            af[6] = (short)f2bf(x1.z); af[7] = (short)f2bf(x1.w);

            float4v acc[8];
#pragma unroll
            for (int c = 0; c < 8; ++c) acc[c] = (float4v){0.f, 0.f, 0.f, 0.f};
#pragma unroll
            for (int c = 0; c < 8; ++c)
                acc[c] = __builtin_amdgcn_mfma_f32_16x16x32_bf16(af, wfr[c], acc[c], 0, 0, 0);

            int rbase = strip + (l >> 4) * 4;
            int m = l & 15;
#pragma unroll
            for (int r = 0; r < 4; ++r) {
                int w0 = __builtin_amdgcn_cvt_pk_fp8_f32(acc[0][r], acc[1][r], 0, false);
                w0     = __builtin_amdgcn_cvt_pk_fp8_f32(acc[2][r], acc[3][r], w0, true);
                int w1 = __builtin_amdgcn_cvt_pk_fp8_f32(acc[4][r], acc[5][r], 0, false);
                w1     = __builtin_amdgcn_cvt_pk_fp8_f32(acc[6][r], acc[7][r], w1, true);
                *((uint2*)(h0f8 + (size_t)(rbase + r) * HDIM + m * 8)) = make_uint2((unsigned)w0, (unsigned)w1);
            }
        }
    }
}

// ---------------------------------------------------------------- kp2: fine CSR within coarse bucket
__global__ __launch_bounds__(256) void kp2_fine(const uint2* __restrict__ scratch,
                                                const int* __restrict__ coarse_cursor,
                                                int2* __restrict__ nbe,
                                                int2* __restrict__ csre) {
    __shared__ int fh[512];
    __shared__ int ts[256];
    __shared__ int ccs[256];

    int b = blockIdx.x, t = threadIdx.x;

    ccs[t] = coarse_cursor[t];
    fh[t] = 0; fh[t + 256] = 0;
    __syncthreads();
    for (int off = 1; off < 256; off <<= 1) {
        int v = (t >= off) ? ccs[t - off] : 0;
        __syncthreads();
        ccs[t] += v;
        __syncthreads();
    }
    int gbase = (b > 0) ? ccs[b - 1] : 0;
    int cnt_b = coarse_cursor[b];
    const uint2* src = scratch + (size_t)b * MAXPER;

    for (int j = t; j < cnt_b; j += 256) {
        uint2 r = src[j];
        atomicAdd(&fh[r.x >> 17], 1);
    }
    __syncthreads();

    int c0 = fh[2 * t], c1 = fh[2 * t + 1];
    int s = c0 + c1;
    ts[t] = s;
    __syncthreads();
    for (int off = 1; off < 256; off <<= 1) {
        int v = (t >= off) ? ts[t - off] : 0;
        __syncthreads();
        ts[t] += v;
        __syncthreads();
    }
    int tb = gbase + ts[t] - s;

    nbe[b * 512 + 2 * t]     = make_int2(tb, tb + c0);
    nbe[b * 512 + 2 * t + 1] = make_int2(tb + c0, tb + c0 + c1);
    __syncthreads();
    fh[2 * t] = tb; fh[2 * t + 1] = tb + c0;
    __syncthreads();

    for (int j = t; j < cnt_b; j += 256) {
        uint2 r = src[j];
        int pos = atomicAdd(&fh[r.x >> 17], 1);
        csre[pos] = make_int2((int)(r.x & 0x1FFFFu), (int)r.y);
    }
}

// ---------------------------------------------------------------- prep
__global__ __launch_bounds__(256) void kprep(const float* __restrict__ Wmsg,
                                             const float* __restrict__ Win,
                                             unsigned short* __restrict__ wfrag,
                                             unsigned short* __restrict__ winfrag,
                                             const int* __restrict__ batch,
                                             int* __restrict__ cnt,
                                             float* __restrict__ gsum,
                                             int* __restrict__ coarse_cursor) {
    int b = blockIdx.x, t = threadIdx.x;
    if (b < 8) {
        int flat = b * 256 + t;
        int l = flat & 63;
        int fragid = flat >> 6;
        int c = fragid >> 2, kk = fragid & 3;
        int col = c * 16 + (l & 15);
        short8v v;
#pragma unroll
        for (int j = 0; j < 8; ++j) {
            int q = kk * 32 + (l >> 4) * 8 + j;          // position-space k
            int krow = (q & 7) * 16 + (q >> 3);          // true k
            v[j] = (short)f2bf(Wmsg[krow * HDIM + col]);
        }
        ((short8v*)wfrag)[flat] = v;
    } else if (b < 10) {
        int flat = (b - 8) * 256 + t;
        int l = flat & 63;
        int c = flat >> 6;
        int col = c * 16 + (l & 15);
        int k0 = (l >> 4) * 8;
        short8v v;
#pragma unroll
        for (int j = 0; j < 8; ++j)
            v[j] = (short)f2bf(Win[(k0 + j) * HDIM + col]);
        ((short8v*)winfrag)[flat] = v;
    } else if (b < 12) {
        int g = (b - 10) * 256 + t;
        if (g < NGRAPH) {
            int lo = 0, hi = NODES;
            while (lo < hi) { int m = (lo + hi) >> 1; if (batch[m] < g) lo = m + 1; else hi = m; }
            int start = lo;
            hi = NODES;
            while (lo < hi) { int m = (lo + hi) >> 1; if (batch[m] < g + 1) lo = m + 1; else hi = m; }
            cnt[g] = lo - start;
        }
    } else if (b < 14) {
        float4* gz = (float4*)gsum;
        int idx = (b - 12) * 256 + t;
        for (int i = idx; i < 16384; i += 512) gz[i] = make_float4(0.f, 0.f, 0.f, 0.f);
    } else {
        coarse_cursor[t] = 0;
    }
}

// ---------------------------------------------------------------- k3b: fused gather + MFMA GEMM + relu + pool
// Phase 1: gather this tile's 128 msg rows into LDS (fp8 rows from h0f8, position space).
// Phase 2: MFMA vs wfrag (LDS), h0-add (fp8 decode), relu, segmented pool.
#define ACC8(r, w) do { \
    float2v q01 = __builtin_amdgcn_cvt_pk_f32_fp8((int)(r).x, false); \
    float2v q23 = __builtin_amdgcn_cvt_pk_f32_fp8((int)(r).x, true);  \
    float2v q45 = __builtin_amdgcn_cvt_pk_f32_fp8((int)(r).y, false); \
    float2v q67 = __builtin_amdgcn_cvt_pk_f32_fp8((int)(r).y, true);  \
    acc0 = fmaf(q01.x, (w), acc0); acc1 = fmaf(q01.y, (w), acc1); \
    acc2 = fmaf(q23.x, (w), acc2); acc3 = fmaf(q23.y, (w), acc3); \
    acc4 = fmaf(q45.x, (w), acc4); acc5 = fmaf(q45.y, (w), acc5); \
    acc6 = fmaf(q67.x, (w), acc6); acc7 = fmaf(q67.y, (w), acc7); \
} while (0)

#define MROW 136   // padded row: 272B -> 16B-aligned, min-bank-slot b128 access

__global__ __launch_bounds__(256) void k3b_fused(const unsigned char* __restrict__ h0f8,
                                                 const int2* __restrict__ nbe,
                                                 const int2* __restrict__ csre,
                                                 const unsigned short* __restrict__ wfrag,
                                                 const int* __restrict__ batch,
                                                 float* __restrict__ gsum) {
    __shared__ __align__(16) unsigned short blds[32 * 64 * 8];   // 32 KB
    __shared__ __align__(16) unsigned short msgL[128][MROW];     // 34 KB
    __shared__ float pool[8][HDIM];                              // 4 KB
    __shared__ int batch_lds[128];

    int t = threadIdx.x;
    int wid = t >> 6, l = t & 63;
    int base = blockIdx.x * 128;

    {
        const uint4* sp = (const uint4*)wfrag;
        uint4* d = (uint4*)blds;
#pragma unroll
        for (int i = 0; i < 8; ++i) d[t + 256 * i] = sp[t + 256 * i];
    }
    if (t < 128) batch_lds[t] = batch[base + t];

    // ---- phase 1: gather 128 msg rows (4 node-streams per wave, 16 lanes/node)
    {
        int grp = l >> 4, m = l & 15;
#pragma unroll
        for (int pass = 0; pass < 8; ++pass) {
            int nl = pass * 16 + wid * 4 + grp;
            int2 be = nbe[base + nl];
            int j = be.x, end = be.y;
            float acc0 = 0.f, acc1 = 0.f, acc2 = 0.f, acc3 = 0.f;
            float acc4 = 0.f, acc5 = 0.f, acc6 = 0.f, acc7 = 0.f;
            for (; j + 4 <= end; j += 4) {
                int2 e0 = csre[j], e1 = csre[j + 1], e2 = csre[j + 2], e3 = csre[j + 3];
                uint2 r0 = ((const uint2*)(h0f8 + (size_t)e0.x * HDIM))[m];
                uint2 r1 = ((const uint2*)(h0f8 + (size_t)e1.x * HDIM))[m];
                uint2 r2 = ((const uint2*)(h0f8 + (size_t)e2.x * HDIM))[m];
                uint2 r3 = ((const uint2*)(h0f8 + (size_t)e3.x * HDIM))[m];
                float w0 = __int_as_float(e0.y), w1 = __int_as_float(e1.y);
                float w2 = __int_as_float(e2.y), w3 = __int_as_float(e3.y);
                ACC8(r0, w0); ACC8(r1, w1); ACC8(r2, w2); ACC8(r3, w3);
            }
            for (; j < end; ++j) {
                int2 e0 = csre[j];
                uint2 r0 = ((const uint2*)(h0f8 + (size_t)e0.x * HDIM))[m];
                float w0 = __int_as_float(e0.y);
                ACC8(r0, w0);
            }
            short8v v;
            v[0] = (short)f2bf(acc0); v[1] = (short)f2bf(acc1);
            v[2] = (short)f2bf(acc2); v[3] = (short)f2bf(acc3);
            v[4] = (short)f2bf(acc4); v[5] = (short)f2bf(acc5);
            v[6] = (short)f2bf(acc6); v[7] = (short)f2bf(acc7);
            *((short8v*)&msgL[nl][m * 8]) = v;
        }
    }
    __syncthreads();

    // ---- phase 2: MFMA + h0-add + relu + pool
    int bfirst = batch_lds[0];
    int blast  = batch_lds[127];
    int span = blast - bfirst + 1;

    const short8v* Bl = (const short8v*)blds;
    int col = l & 15;

    if (span <= 2) {
        float pa[8], pb[8];
#pragma unroll
        for (int c = 0; c < 8; ++c) { pa[c] = 0.f; pb[c] = 0.f; }

#pragma unroll
        for (int s = 0; s < 2; ++s) {
            int lrow = wid * 32 + s * 16 + col;
            short8v af[4];
#pragma unroll
            for (int kk = 0; kk < 4; ++kk)
                af[kk] = *((const short8v*)&msgL[lrow][(kk * 4 + (l >> 4)) * 8]);
            int rbase = base + wid * 32 + s * 16 + (l >> 4) * 4;
            uint2 h8[4];
#pragma unroll
            for (int r = 0; r < 4; ++r)
                h8[r] = *((const uint2*)(h0f8 + (size_t)(rbase + r) * HDIM + col * 8));

            float4v acc[8];
#pragma unroll
            for (int c = 0; c < 8; ++c) acc[c] = (float4v){0.f, 0.f, 0.f, 0.f};
#pragma unroll
            for (int kk = 0; kk < 4; ++kk)
#pragma unroll
                for (int c = 0; c < 8; ++c)
                    acc[c] = __builtin_amdgcn_mfma_f32_16x16x32_bf16(af[kk], Bl[(c * 4 + kk) * 64 + l], acc[c], 0, 0, 0);

#pragma unroll
            for (int r = 0; r < 4; ++r) {
                bool isA = (batch_lds[rbase + r - base] == bfirst);
                float h0v[8];
                dec8(h8[r], h0v);
#pragma unroll
                for (int c = 0; c < 8; ++c) {
                    float hv = fmaxf(h0v[c] + acc[c][r], 0.f);
                    pa[c] += isA ? hv : 0.f;
                    pb[c] += isA ? 0.f : hv;
                }
            }
        }
#pragma unroll
        for (int c = 0; c < 8; ++c) {
            pa[c] += __shfl_xor(pa[c], 16);
            pa[c] += __shfl_xor(pa[c], 32);
            pb[c] += __shfl_xor(pb[c], 16);
            pb[c] += __shfl_xor(pb[c], 32);
        }
        float (*p2)[2][HDIM] = (float (*)[2][HDIM])pool;
        if (l < 16) {
#pragma unroll
            for (int c = 0; c < 8; ++c) {
                p2[wid][0][c * 16 + l] = pa[c];
                p2[wid][1][c * 16 + l] = pb[c];
            }
        }
        __syncthreads();
        int cc2 = t & 127, sidx = t >> 7;
        if (sidx < span) {
            float v = p2[0][sidx][cc2] + p2[1][sidx][cc2] + p2[2][sidx][cc2] + p2[3][sidx][cc2];
            atomicAdd(&gsum[(size_t)(bfirst + sidx) * HDIM + cc2], v);
        }
    } else {
        bool lds_pool = (span <= 8);
        if (lds_pool) {
            float* pf = (float*)pool;
            for (int i = t; i < 8 * HDIM; i += 256) pf[i] = 0.f;
        }
        __syncthreads();

#pragma unroll
        for (int s = 0; s < 2; ++s) {
            int lrow = wid * 32 + s * 16 + col;
            short8v af[4];
#pragma unroll
            for (int kk = 0; kk < 4; ++kk)
                af[kk] = *((const short8v*)&msgL[lrow][(kk * 4 + (l >> 4)) * 8]);
            int rbase = base + wid * 32 + s * 16 + (l >> 4) * 4;
            uint2 h8[4];
#pragma unroll
            for (int r = 0; r < 4; ++r)
                h8[r] = *((const uint2*)(h0f8 + (size_t)(rbase + r) * HDIM + col * 8));

            float4v acc[8];
#pragma unroll
            for (int c = 0; c < 8; ++c) acc[c] = (float4v){0.f, 0.f, 0.f, 0.f};
#pragma unroll
            for (int kk = 0; kk < 4; ++kk)
#pragma unroll
                for (int c = 0; c < 8; ++c)
                    acc[c] = __builtin_amdgcn_mfma_f32_16x16x32_bf16(af[kk], Bl[(c * 4 + kk) * 64 + l], acc[c], 0, 0, 0);

            if (lds_pool) {
#pragma unroll
                for (int r = 0; r < 4; ++r) {
                    int g = batch_lds[rbase + r - base] - bfirst;
                    float h0v[8];
                    dec8(h8[r], h0v);
#pragma unroll
                    for (int c = 0; c < 8; ++c) {
                        float hv = fmaxf(h0v[c] + acc[c][r], 0.f);
                        atomicAdd(&pool[g][c * 16 + col], hv);
                    }
                }
            } else {
#pragma unroll
                for (int r = 0; r < 4; ++r) {
                    int g = batch_lds[rbase + r - base];
                    float h0v[8];
                    dec8(h8[r], h0v);
#pragma unroll
                    for (int c = 0; c < 8; ++c) {
                        float hv = fmaxf(h0v[c] + acc[c][r], 0.f);
                        atomicAdd(&gsum[(size_t)g * HDIM + c * 16 + col], hv);
                    }
                }
            }
        }
        __syncthreads();
        if (lds_pool) {
            int cc2 = t & 127;
            for (int s2 = t >> 7; s2 < span; s2 += 2)
                atomicAdd(&gsum[(size_t)(bfirst + s2) * HDIM + cc2], pool[s2][cc2]);
        }
    }
}

// ---------------------------------------------------------------- k4a: backbone + value head
__global__ __launch_bounds__(128) void k4a_backbone(const float* __restrict__ gsum,
                                                    const int* __restrict__ cnt,
                                                    const float* __restrict__ W1,
                                                    const float* __restrict__ W2,
                                                    const float* __restrict__ Wv1,
                                                    const float* __restrict__ Wv2,
                                                    float* __restrict__ s2g,
                                                    float* __restrict__ out) {
    int g = blockIdx.x;
    int t = threadIdx.x;
    __shared__ float gv[HDIM];
    __shared__ float s1[HDIM];
    __shared__ float s2v[64];
    __shared__ float v1[32];

    {
        int c = cnt[g];
        gv[t] = (c > 0) ? gsum[(size_t)g * HDIM + t] / (float)c : 0.f;
    }
    __syncthreads();

    {
        float s = 0.f;
#pragma unroll 8
        for (int k = 0; k < HDIM; ++k)
            s = fmaf(gv[k], W1[k * HDIM + t] + W1[(k + HDIM) * HDIM + t], s);
        s1[t] = fmaxf(s, 0.f);
    }
    __syncthreads();

    if (t < 64) {
        float s = 0.f;
#pragma unroll 8
        for (int k = 0; k < HDIM; ++k)
            s = fmaf(s1[k], W2[k * 64 + t], s);
        float sv = fmaxf(s, 0.f);
        s2v[t] = sv;
        s2g[(size_t)g * 64 + t] = sv;
    }
    __syncthreads();

    if (t < 32) {
        float s = 0.f;
#pragma unroll 8
        for (int k = 0; k < 64; ++k)
            s = fmaf(s2v[k], Wv1[k * 32 + t], s);
        v1[t] = fmaxf(s, 0.f);
    }
    __syncthreads();
    if (t == 0) {
        float s = 0.f;
#pragma unroll
        for (int k = 0; k < 32; ++k)
            s = fmaf(v1[k], Wv2[k], s);
        out[1028608 + (size_t)g] = tanhf(s);
    }
}

// ---------------------------------------------------------------- k4b: logits GEMM [512,64]@[64,2009]
__global__ __launch_bounds__(256) void k4b_logits(const float* __restrict__ s2g,
                                                  const float* __restrict__ Wa,
                                                  const float* __restrict__ Ws,
                                                  const float* __restrict__ Wt,
                                                  const float* __restrict__ Wact,
                                                  float* __restrict__ out) {
    int ctile = blockIdx.x & 7;
    int gbase = (blockIdx.x >> 3) * 16;
    int t = threadIdx.x;
    int col = ctile * 256 + t;

    __shared__ float4 s2s4[16][16];
    {
        int g = t >> 4, q = t & 15;
        s2s4[g][q] = ((const float4*)(s2g + (size_t)(gbase + g) * 64))[q];
    }

    bool valid = (col < 2009);
    const float* W = Wa; int colc = 0, ncol = 5; size_t hb = 0;
    if (col < 5)        { W = Wa;   colc = col;        ncol = 5;    hb = 0; }
    else if (col < 1005){ W = Ws;   colc = col - 5;    ncol = 1000; hb = 2560; }
    else if (col < 2005){ W = Wt;   colc = col - 1005; ncol = 1000; hb = 514560; }
    else                { W = Wact; colc = col - 2005; ncol = 4;    hb = 1026560; }

    float wr[64];
#pragma unroll
    for (int k = 0; k < 64; ++k)
        wr[k] = valid ? W[(size_t)k * ncol + colc] : 0.f;
    __syncthreads();

    for (int gg = 0; gg < 16; ++gg) {
        const float4* s4 = (const float4*)s2s4[gg];
        float a = 0.f;
#pragma unroll
        for (int q = 0; q < 16; ++q) {
            float4 v = s4[q];
            a = fmaf(v.x, wr[4 * q + 0], a);
            a = fmaf(v.y, wr[4 * q + 1], a);
            a = fmaf(v.z, wr[4 * q + 2], a);
            a = fmaf(v.w, wr[4 * q + 3], a);
        }
        if (valid) out[hb + (size_t)(gbase + gg) * ncol + colc] = a;
    }
}

// ----------------------------------------------------------------
extern "C" void kernel_launch(void* const* d_in, const int* in_sizes, int n_in,
                              void* d_out, int out_size, void* d_ws, size_t ws_size,
                              hipStream_t stream) {
    const float* x     = (const float*)d_in[0];
    const int*   ei    = (const int*)d_in[1];
    const float* ew    = (const float*)d_in[2];
    const int*   batch = (const int*)d_in[4];
    const float* Win   = (const float*)d_in[6];
    const float* Wmsg  = (const float*)d_in[7];
    const float* W1    = (const float*)d_in[8];
    const float* W2    = (const float*)d_in[9];
    const float* Wa    = (const float*)d_in[10];
    const float* Ws    = (const float*)d_in[11];
    const float* Wt    = (const float*)d_in[12];
    const float* Wact  = (const float*)d_in[13];
    const float* Wv1   = (const float*)d_in[14];
    const float* Wv2   = (const float*)d_in[15];
    float* out = (float*)d_out;

    char* p = (char*)d_ws;
    unsigned char*  h0f8   = (unsigned char*)p;   p += (size_t)NODES * HDIM;   // 16 MB
    float*          gsum   = (float*)p;           p += (size_t)NGRAPH * HDIM * 4;
    float*          s2g    = (float*)p;           p += (size_t)NGRAPH * 64 * 4;
    unsigned short* wfrag  = (unsigned short*)p;  p += 32 * 64 * 16;
    unsigned short* winfrag= (unsigned short*)p;  p += 8 * 64 * 16;
    int*            cnt    = (int*)p;             p += (size_t)NGRAPH * 4;
    int*            ccur   = (int*)p;             p += NB * 4;
    uint2*          scratch= (uint2*)p;           p += (size_t)NB * MAXPER * 8;   // 10.5 MB
    int2*           nbe    = (int2*)p;            p += (size_t)NODES * 8;
    int2*           csre   = (int2*)p;            p += (size_t)EDGES * 8;

    kprep        <<<15, 256, 0, stream>>>(Wmsg, Win, wfrag, winfrag, batch, cnt, gsum, ccur);
    k1_fused     <<<NB + 1024, 256, 0, stream>>>(x, winfrag, h0f8, ei, ew, ccur, scratch);
    kp2_fine     <<<NB, 256, 0, stream>>>(scratch, ccur, nbe, csre);

    k3b_fused    <<<NODES / 128, 256, 0, stream>>>(h0f8, nbe, csre, wfrag, batch, gsum);

    k4a_backbone <<<NGRAPH, 128, 0, stream>>>(gsum, cnt, W1, W2, Wv1, Wv2, s2g, out);
    k4b_logits   <<<256, 256, 0, stream>>>(s2g, Wa, Ws, Wt, Wact, out);
}

// Round 14
// 114.332 us; speedup vs baseline: 1.2423x; 1.2423x over previous
//
#include <hip/hip_runtime.h>
#include <math.h>

#define NODES   131072
#define EDGES   1048576
#define FDIM    32
#define HDIM    128
#define NGRAPH  512

#define NB      256         // coarse buckets
#define BSH     9           // tgt>>9 -> bucket; 512 nodes per bucket
#define MAXPER  5120        // slots per bucket
#define EPB     4096        // edges per partition block

typedef __attribute__((ext_vector_type(8))) short short8v;
typedef __attribute__((ext_vector_type(4))) float float4v;
typedef __attribute__((ext_vector_type(2))) float float2v;

__device__ __forceinline__ unsigned short f2bf(float f) {
    union { float f; unsigned int u; } v; v.f = f;
    unsigned int u = v.u;
    unsigned int r = (u + 0x7fffu + ((u >> 16) & 1u)) >> 16;   // RNE
    return (unsigned short)r;
}

// decode 8 fp8 (positions m*8..m*8+7) -> true cols c*16+m for c=0..7
__device__ __forceinline__ void dec8(uint2 r, float* o) {
    float2v a = __builtin_amdgcn_cvt_pk_f32_fp8((int)r.x, false);
    float2v b = __builtin_amdgcn_cvt_pk_f32_fp8((int)r.x, true);
    float2v c = __builtin_amdgcn_cvt_pk_f32_fp8((int)r.y, false);
    float2v d = __builtin_amdgcn_cvt_pk_f32_fp8((int)r.y, true);
    o[0] = a.x; o[1] = a.y; o[2] = b.x; o[3] = b.y;
    o[4] = c.x; o[5] = c.y; o[6] = d.x; o[7] = d.y;
}

// ---------------------------------------------------------------- k1_fused: [0,NB) edge partition | [NB,NB+1024) MFMA projection
__global__ __launch_bounds__(256) void k1_fused(const float* __restrict__ x,
                                                const unsigned short* __restrict__ winfrag,
                                                unsigned char* __restrict__ h0f8,
                                                const int* __restrict__ ei,
                                                const float* __restrict__ ew,
                                                int* __restrict__ coarse_cursor,
                                                uint2* __restrict__ scratch) {
    __shared__ __align__(16) uint2 recL[EPB];     // 32KB
    __shared__ unsigned char bidL[EPB];           // 4KB
    __shared__ int hist[NB];
    __shared__ int excl[NB];
    __shared__ int gb[NB];

    int b = blockIdx.x, t = threadIdx.x;

    if (b < NB) {
        int e0 = b * EPB;
        hist[t] = 0;
        __syncthreads();

        unsigned int rx[16], rw[16];
        int bb[16], lr[16];
#pragma unroll
        for (int i = 0; i < 16; ++i) {
            int e = e0 + t + 256 * i;
            int src = ei[e];
            int tgt = ei[EDGES + e];
            float w = ew[e];
            int bk = tgt >> BSH;
            rx[i] = (unsigned int)src | ((unsigned int)(tgt & ((1 << BSH) - 1)) << 17);
            rw[i] = __float_as_uint(w);
            bb[i] = bk;
            lr[i] = atomicAdd(&hist[bk], 1);
        }
        __syncthreads();

        int hv = hist[t];
        excl[t] = hv;
        __syncthreads();
        for (int off = 1; off < 256; off <<= 1) {
            int v = (t >= off) ? excl[t - off] : 0;
            __syncthreads();
            excl[t] += v;
            __syncthreads();
        }
        int ex = excl[t] - hv;
        gb[t] = atomicAdd(&coarse_cursor[t], hv);
        __syncthreads();
        excl[t] = ex;
        __syncthreads();

#pragma unroll
        for (int i = 0; i < 16; ++i) {
            int pos = excl[bb[i]] + lr[i];
            recL[pos] = make_uint2(rx[i], rw[i]);
            bidL[pos] = (unsigned char)bb[i];
        }
        __syncthreads();

#pragma unroll
        for (int i = 0; i < 16; ++i) {
            int p2 = t + 256 * i;
            int bk = bidL[p2];
            int dst = bk * MAXPER + gb[bk] + (p2 - excl[bk]);
            scratch[dst] = recL[p2];
        }
    } else {
        int mb = b - NB;
        int wid = t >> 6, l = t & 63;
        int base = mb * 128;

        const short8v* wf8 = (const short8v*)winfrag;
        short8v wfr[8];
#pragma unroll
        for (int c = 0; c < 8; ++c) wfr[c] = wf8[c * 64 + l];

#pragma unroll
        for (int s = 0; s < 2; ++s) {
            int strip = base + wid * 32 + s * 16;
            int row = strip + (l & 15);
            const float* xr = x + (size_t)row * FDIM + (l >> 4) * 8;
            float4 x0 = ((const float4*)xr)[0];
            float4 x1 = ((const float4*)xr)[1];
            short8v af;
            af[0] = (short)f2bf(x0.x); af[1] = (short)f2bf(x0.y);
            af[2] = (short)f2bf(x0.z); af[3] = (short)f2bf(x0.w);
            af[4] = (short)f2bf(x1.x); af[5] = (short)f2bf(x1.y);
            af[6] = (short)f2bf(x1.z); af[7] = (short)f2bf(x1.w);

            float4v acc[8];
#pragma unroll
            for (int c = 0; c < 8; ++c) acc[c] = (float4v){0.f, 0.f, 0.f, 0.f};
#pragma unroll
            for (int c = 0; c < 8; ++c)
                acc[c] = __builtin_amdgcn_mfma_f32_16x16x32_bf16(af, wfr[c], acc[c], 0, 0, 0);

            int rbase = strip + (l >> 4) * 4;
            int m = l & 15;
#pragma unroll
            for (int r = 0; r < 4; ++r) {
                int w0 = __builtin_amdgcn_cvt_pk_fp8_f32(acc[0][r], acc[1][r], 0, false);
                w0     = __builtin_amdgcn_cvt_pk_fp8_f32(acc[2][r], acc[3][r], w0, true);
                int w1 = __builtin_amdgcn_cvt_pk_fp8_f32(acc[4][r], acc[5][r], 0, false);
                w1     = __builtin_amdgcn_cvt_pk_fp8_f32(acc[6][r], acc[7][r], w1, true);
                *((uint2*)(h0f8 + (size_t)(rbase + r) * HDIM + m * 8)) = make_uint2((unsigned)w0, (unsigned)w1);
            }
        }
    }
}

// ---------------------------------------------------------------- kp2: fine CSR within coarse bucket
__global__ __launch_bounds__(256) void kp2_fine(const uint2* __restrict__ scratch,
                                                const int* __restrict__ coarse_cursor,
                                                int2* __restrict__ nbe,
                                                int2* __restrict__ csre) {
    __shared__ int fh[512];
    __shared__ int ts[256];
    __shared__ int ccs[256];

    int b = blockIdx.x, t = threadIdx.x;

    ccs[t] = coarse_cursor[t];
    fh[t] = 0; fh[t + 256] = 0;
    __syncthreads();
    for (int off = 1; off < 256; off <<= 1) {
        int v = (t >= off) ? ccs[t - off] : 0;
        __syncthreads();
        ccs[t] += v;
        __syncthreads();
    }
    int gbase = (b > 0) ? ccs[b - 1] : 0;
    int cnt_b = coarse_cursor[b];
    const uint2* src = scratch + (size_t)b * MAXPER;

    for (int j = t; j < cnt_b; j += 256) {
        uint2 r = src[j];
        atomicAdd(&fh[r.x >> 17], 1);
    }
    __syncthreads();

    int c0 = fh[2 * t], c1 = fh[2 * t + 1];
    int s = c0 + c1;
    ts[t] = s;
    __syncthreads();
    for (int off = 1; off < 256; off <<= 1) {
        int v = (t >= off) ? ts[t - off] : 0;
        __syncthreads();
        ts[t] += v;
        __syncthreads();
    }
    int tb = gbase + ts[t] - s;

    nbe[b * 512 + 2 * t]     = make_int2(tb, tb + c0);
    nbe[b * 512 + 2 * t + 1] = make_int2(tb + c0, tb + c0 + c1);
    __syncthreads();
    fh[2 * t] = tb; fh[2 * t + 1] = tb + c0;
    __syncthreads();

    for (int j = t; j < cnt_b; j += 256) {
        uint2 r = src[j];
        int pos = atomicAdd(&fh[r.x >> 17], 1);
        csre[pos] = make_int2((int)(r.x & 0x1FFFFu), (int)r.y);
    }
}

// ---------------------------------------------------------------- prep
__global__ __launch_bounds__(256) void kprep(const float* __restrict__ Wmsg,
                                             const float* __restrict__ Win,
                                             unsigned short* __restrict__ wfrag,
                                             unsigned short* __restrict__ winfrag,
                                             const int* __restrict__ batch,
                                             int* __restrict__ cnt,
                                             float* __restrict__ gsum,
                                             int* __restrict__ coarse_cursor) {
    int b = blockIdx.x, t = threadIdx.x;
    if (b < 8) {
        int flat = b * 256 + t;
        int l = flat & 63;
        int fragid = flat >> 6;
        int c = fragid >> 2, kk = fragid & 3;
        int col = c * 16 + (l & 15);
        short8v v;
#pragma unroll
        for (int j = 0; j < 8; ++j) {
            int q = kk * 32 + (l >> 4) * 8 + j;          // position-space k
            int krow = (q & 7) * 16 + (q >> 3);          // true k
            v[j] = (short)f2bf(Wmsg[krow * HDIM + col]);
        }
        ((short8v*)wfrag)[flat] = v;
    } else if (b < 10) {
        int flat = (b - 8) * 256 + t;
        int l = flat & 63;
        int c = flat >> 6;
        int col = c * 16 + (l & 15);
        int k0 = (l >> 4) * 8;
        short8v v;
#pragma unroll
        for (int j = 0; j < 8; ++j)
            v[j] = (short)f2bf(Win[(k0 + j) * HDIM + col]);
        ((short8v*)winfrag)[flat] = v;
    } else if (b < 12) {
        int g = (b - 10) * 256 + t;
        if (g < NGRAPH) {
            int lo = 0, hi = NODES;
            while (lo < hi) { int m = (lo + hi) >> 1; if (batch[m] < g) lo = m + 1; else hi = m; }
            int start = lo;
            hi = NODES;
            while (lo < hi) { int m = (lo + hi) >> 1; if (batch[m] < g + 1) lo = m + 1; else hi = m; }
            cnt[g] = lo - start;
        }
    } else if (b < 14) {
        float4* gz = (float4*)gsum;
        int idx = (b - 12) * 256 + t;
        for (int i = idx; i < 16384; i += 512) gz[i] = make_float4(0.f, 0.f, 0.f, 0.f);
    } else {
        coarse_cursor[t] = 0;
    }
}

// ---------------------------------------------------------------- gather: 4 nodes per wave, 16 lanes/node
// unroll-8 leading loop: up to 8 row-loads in flight per stream (32/wave)
#define ACC8(r, w) do { \
    float2v q01 = __builtin_amdgcn_cvt_pk_f32_fp8((int)(r).x, false); \
    float2v q23 = __builtin_amdgcn_cvt_pk_f32_fp8((int)(r).x, true);  \
    float2v q45 = __builtin_amdgcn_cvt_pk_f32_fp8((int)(r).y, false); \
    float2v q67 = __builtin_amdgcn_cvt_pk_f32_fp8((int)(r).y, true);  \
    acc0 = fmaf(q01.x, (w), acc0); acc1 = fmaf(q01.y, (w), acc1); \
    acc2 = fmaf(q23.x, (w), acc2); acc3 = fmaf(q23.y, (w), acc3); \
    acc4 = fmaf(q45.x, (w), acc4); acc5 = fmaf(q45.y, (w), acc5); \
    acc6 = fmaf(q67.x, (w), acc6); acc7 = fmaf(q67.y, (w), acc7); \
} while (0)

__global__ __launch_bounds__(256) void kg_gather(const unsigned char* __restrict__ h0f8,
                                                 const int2* __restrict__ nbe,
                                                 const int2* __restrict__ csre,
                                                 unsigned short* __restrict__ msgb, int N) {
    int t = threadIdx.x;
    int wid = t >> 6, l = t & 63;
    int grp = l >> 4, m = l & 15;
    int n = blockIdx.x * 16 + wid * 4 + grp;

    int2 be = nbe[n];
    int j = be.x, end = be.y;
    float acc0 = 0.f, acc1 = 0.f, acc2 = 0.f, acc3 = 0.f;
    float acc4 = 0.f, acc5 = 0.f, acc6 = 0.f, acc7 = 0.f;

    for (; j + 8 <= end; j += 8) {
        int2 e0 = csre[j],     e1 = csre[j + 1], e2 = csre[j + 2], e3 = csre[j + 3];
        int2 e4 = csre[j + 4], e5 = csre[j + 5], e6 = csre[j + 6], e7 = csre[j + 7];
        uint2 r0 = ((const uint2*)(h0f8 + (size_t)e0.x * HDIM))[m];
        uint2 r1 = ((const uint2*)(h0f8 + (size_t)e1.x * HDIM))[m];
        uint2 r2 = ((const uint2*)(h0f8 + (size_t)e2.x * HDIM))[m];
        uint2 r3 = ((const uint2*)(h0f8 + (size_t)e3.x * HDIM))[m];
        uint2 r4 = ((const uint2*)(h0f8 + (size_t)e4.x * HDIM))[m];
        uint2 r5 = ((const uint2*)(h0f8 + (size_t)e5.x * HDIM))[m];
        uint2 r6 = ((const uint2*)(h0f8 + (size_t)e6.x * HDIM))[m];
        uint2 r7 = ((const uint2*)(h0f8 + (size_t)e7.x * HDIM))[m];
        float w0 = __int_as_float(e0.y), w1 = __int_as_float(e1.y);
        float w2 = __int_as_float(e2.y), w3 = __int_as_float(e3.y);
        float w4 = __int_as_float(e4.y), w5 = __int_as_float(e5.y);
        float w6 = __int_as_float(e6.y), w7 = __int_as_float(e7.y);
        ACC8(r0, w0); ACC8(r1, w1); ACC8(r2, w2); ACC8(r3, w3);
        ACC8(r4, w4); ACC8(r5, w5); ACC8(r6, w6); ACC8(r7, w7);
    }
    for (; j + 4 <= end; j += 4) {
        int2 e0 = csre[j], e1 = csre[j + 1], e2 = csre[j + 2], e3 = csre[j + 3];
        uint2 r0 = ((const uint2*)(h0f8 + (size_t)e0.x * HDIM))[m];
        uint2 r1 = ((const uint2*)(h0f8 + (size_t)e1.x * HDIM))[m];
        uint2 r2 = ((const uint2*)(h0f8 + (size_t)e2.x * HDIM))[m];
        uint2 r3 = ((const uint2*)(h0f8 + (size_t)e3.x * HDIM))[m];
        float w0 = __int_as_float(e0.y), w1 = __int_as_float(e1.y);
        float w2 = __int_as_float(e2.y), w3 = __int_as_float(e3.y);
        ACC8(r0, w0); ACC8(r1, w1); ACC8(r2, w2); ACC8(r3, w3);
    }
    for (; j < end; ++j) {
        int2 e0 = csre[j];
        uint2 r0 = ((const uint2*)(h0f8 + (size_t)e0.x * HDIM))[m];
        float w0 = __int_as_float(e0.y);
        ACC8(r0, w0);
    }

    short8v v;
    v[0] = (short)f2bf(acc0); v[1] = (short)f2bf(acc1);
    v[2] = (short)f2bf(acc2); v[3] = (short)f2bf(acc3);
    v[4] = (short)f2bf(acc4); v[5] = (short)f2bf(acc5);
    v[6] = (short)f2bf(acc6); v[7] = (short)f2bf(acc7);
    ((short8v*)(msgb + (size_t)n * HDIM))[m] = v;
}

// ---------------------------------------------------------------- k3a: MFMA GEMM + relu + pool (h0 term decoded from fp8)
__global__ __launch_bounds__(256) void k3a_mfma_pool(const unsigned short* __restrict__ msgb,
                                                     const unsigned char* __restrict__ h0f8,
                                                     const unsigned short* __restrict__ wfrag,
                                                     const int* __restrict__ batch,
                                                     float* __restrict__ gsum) {
    __shared__ __align__(16) unsigned short blds[32 * 64 * 8];  // 32KB
    __shared__ float pool[8][HDIM];
    __shared__ int batch_lds[128];

    int t = threadIdx.x;
    int wid = t >> 6, l = t & 63;
    int base = blockIdx.x * 128;

    {
        const uint4* sp = (const uint4*)wfrag;
        uint4* d = (uint4*)blds;
#pragma unroll
        for (int i = 0; i < 8; ++i) d[t + 256 * i] = sp[t + 256 * i];
    }
    if (t < 128) batch_lds[t] = batch[base + t];
    __syncthreads();

    int bfirst = batch_lds[0];
    int blast  = batch_lds[127];
    int span = blast - bfirst + 1;

    const short8v* Bl = (const short8v*)blds;
    int col = l & 15;

    if (span <= 2) {
        float pa[8], pb[8];
#pragma unroll
        for (int c = 0; c < 8; ++c) { pa[c] = 0.f; pb[c] = 0.f; }

#pragma unroll
        for (int s = 0; s < 2; ++s) {
            int strip = base + wid * 32 + s * 16;
            const short8v* mrow = (const short8v*)(msgb + (size_t)(strip + col) * HDIM);
            short8v af[4];
#pragma unroll
            for (int kk = 0; kk < 4; ++kk) af[kk] = mrow[kk * 4 + (l >> 4)];
            int rbase = strip + (l >> 4) * 4;
            uint2 h8[4];
#pragma unroll
            for (int r = 0; r < 4; ++r)
                h8[r] = *((const uint2*)(h0f8 + (size_t)(rbase + r) * HDIM + col * 8));

            float4v acc[8];
#pragma unroll
            for (int c = 0; c < 8; ++c) acc[c] = (float4v){0.f, 0.f, 0.f, 0.f};
#pragma unroll
            for (int kk = 0; kk < 4; ++kk)
#pragma unroll
                for (int c = 0; c < 8; ++c)
                    acc[c] = __builtin_amdgcn_mfma_f32_16x16x32_bf16(af[kk], Bl[(c * 4 + kk) * 64 + l], acc[c], 0, 0, 0);

#pragma unroll
            for (int r = 0; r < 4; ++r) {
                bool isA = (batch_lds[rbase + r - base] == bfirst);
                float h0v[8];
                dec8(h8[r], h0v);
#pragma unroll
                for (int c = 0; c < 8; ++c) {
                    float hv = fmaxf(h0v[c] + acc[c][r], 0.f);
                    pa[c] += isA ? hv : 0.f;
                    pb[c] += isA ? 0.f : hv;
                }
            }
        }
#pragma unroll
        for (int c = 0; c < 8; ++c) {
            pa[c] += __shfl_xor(pa[c], 16);
            pa[c] += __shfl_xor(pa[c], 32);
            pb[c] += __shfl_xor(pb[c], 16);
            pb[c] += __shfl_xor(pb[c], 32);
        }
        float (*p2)[2][HDIM] = (float (*)[2][HDIM])pool;
        if (l < 16) {
#pragma unroll
            for (int c = 0; c < 8; ++c) {
                p2[wid][0][c * 16 + l] = pa[c];
                p2[wid][1][c * 16 + l] = pb[c];
            }
        }
        __syncthreads();
        int cc2 = t & 127, sidx = t >> 7;
        if (sidx < span) {
            float v = p2[0][sidx][cc2] + p2[1][sidx][cc2] + p2[2][sidx][cc2] + p2[3][sidx][cc2];
            atomicAdd(&gsum[(size_t)(bfirst + sidx) * HDIM + cc2], v);
        }
    } else {
        bool lds_pool = (span <= 8);
        if (lds_pool) {
            float* pf = (float*)pool;
            for (int i = t; i < 8 * HDIM; i += 256) pf[i] = 0.f;
        }
        __syncthreads();

#pragma unroll
        for (int s = 0; s < 2; ++s) {
            int strip = base + wid * 32 + s * 16;
            const short8v* mrow = (const short8v*)(msgb + (size_t)(strip + col) * HDIM);
            short8v af[4];
#pragma unroll
            for (int kk = 0; kk < 4; ++kk) af[kk] = mrow[kk * 4 + (l >> 4)];
            int rbase = strip + (l >> 4) * 4;
            uint2 h8[4];
#pragma unroll
            for (int r = 0; r < 4; ++r)
                h8[r] = *((const uint2*)(h0f8 + (size_t)(rbase + r) * HDIM + col * 8));

            float4v acc[8];
#pragma unroll
            for (int c = 0; c < 8; ++c) acc[c] = (float4v){0.f, 0.f, 0.f, 0.f};
#pragma unroll
            for (int kk = 0; kk < 4; ++kk)
#pragma unroll
                for (int c = 0; c < 8; ++c)
                    acc[c] = __builtin_amdgcn_mfma_f32_16x16x32_bf16(af[kk], Bl[(c * 4 + kk) * 64 + l], acc[c], 0, 0, 0);

            if (lds_pool) {
#pragma unroll
                for (int r = 0; r < 4; ++r) {
                    int g = batch_lds[rbase + r - base] - bfirst;
                    float h0v[8];
                    dec8(h8[r], h0v);
#pragma unroll
                    for (int c = 0; c < 8; ++c) {
                        float hv = fmaxf(h0v[c] + acc[c][r], 0.f);
                        atomicAdd(&pool[g][c * 16 + col], hv);
                    }
                }
            } else {
#pragma unroll
                for (int r = 0; r < 4; ++r) {
                    int g = batch_lds[rbase + r - base];
                    float h0v[8];
                    dec8(h8[r], h0v);
#pragma unroll
                    for (int c = 0; c < 8; ++c) {
                        float hv = fmaxf(h0v[c] + acc[c][r], 0.f);
                        atomicAdd(&gsum[(size_t)g * HDIM + c * 16 + col], hv);
                    }
                }
            }
        }
        __syncthreads();
        if (lds_pool) {
            int cc2 = t & 127;
            for (int s2 = t >> 7; s2 < span; s2 += 2)
                atomicAdd(&gsum[(size_t)(bfirst + s2) * HDIM + cc2], pool[s2][cc2]);
        }
    }
}

// ---------------------------------------------------------------- k4a: backbone + value head
__global__ __launch_bounds__(128) void k4a_backbone(const float* __restrict__ gsum,
                                                    const int* __restrict__ cnt,
                                                    const float* __restrict__ W1,
                                                    const float* __restrict__ W2,
                                                    const float* __restrict__ Wv1,
                                                    const float* __restrict__ Wv2,
                                                    float* __restrict__ s2g,
                                                    float* __restrict__ out) {
    int g = blockIdx.x;
    int t = threadIdx.x;
    __shared__ float gv[HDIM];
    __shared__ float s1[HDIM];
    __shared__ float s2v[64];
    __shared__ float v1[32];

    {
        int c = cnt[g];
        gv[t] = (c > 0) ? gsum[(size_t)g * HDIM + t] / (float)c : 0.f;
    }
    __syncthreads();

    {
        float s = 0.f;
#pragma unroll 8
        for (int k = 0; k < HDIM; ++k)
            s = fmaf(gv[k], W1[k * HDIM + t] + W1[(k + HDIM) * HDIM + t], s);
        s1[t] = fmaxf(s, 0.f);
    }
    __syncthreads();

    if (t < 64) {
        float s = 0.f;
#pragma unroll 8
        for (int k = 0; k < HDIM; ++k)
            s = fmaf(s1[k], W2[k * 64 + t], s);
        float sv = fmaxf(s, 0.f);
        s2v[t] = sv;
        s2g[(size_t)g * 64 + t] = sv;
    }
    __syncthreads();

    if (t < 32) {
        float s = 0.f;
#pragma unroll 8
        for (int k = 0; k < 64; ++k)
            s = fmaf(s2v[k], Wv1[k * 32 + t], s);
        v1[t] = fmaxf(s, 0.f);
    }
    __syncthreads();
    if (t == 0) {
        float s = 0.f;
#pragma unroll
        for (int k = 0; k < 32; ++k)
            s = fmaf(v1[k], Wv2[k], s);
        out[1028608 + (size_t)g] = tanhf(s);
    }
}

// ---------------------------------------------------------------- k4b: logits GEMM [512,64]@[64,2009]
__global__ __launch_bounds__(256) void k4b_logits(const float* __restrict__ s2g,
                                                  const float* __restrict__ Wa,
                                                  const float* __restrict__ Ws,
                                                  const float* __restrict__ Wt,
                                                  const float* __restrict__ Wact,
                                                  float* __restrict__ out) {
    int ctile = blockIdx.x & 7;
    int gbase = (blockIdx.x >> 3) * 16;
    int t = threadIdx.x;
    int col = ctile * 256 + t;

    __shared__ float4 s2s4[16][16];
    {
        int g = t >> 4, q = t & 15;
        s2s4[g][q] = ((const float4*)(s2g + (size_t)(gbase + g) * 64))[q];
    }

    bool valid = (col < 2009);
    const float* W = Wa; int colc = 0, ncol = 5; size_t hb = 0;
    if (col < 5)        { W = Wa;   colc = col;        ncol = 5;    hb = 0; }
    else if (col < 1005){ W = Ws;   colc = col - 5;    ncol = 1000; hb = 2560; }
    else if (col < 2005){ W = Wt;   colc = col - 1005; ncol = 1000; hb = 514560; }
    else                { W = Wact; colc = col - 2005; ncol = 4;    hb = 1026560; }

    float wr[64];
#pragma unroll
    for (int k = 0; k < 64; ++k)
        wr[k] = valid ? W[(size_t)k * ncol + colc] : 0.f;
    __syncthreads();

    for (int gg = 0; gg < 16; ++gg) {
        const float4* s4 = (const float4*)s2s4[gg];
        float a = 0.f;
#pragma unroll
        for (int q = 0; q < 16; ++q) {
            float4 v = s4[q];
            a = fmaf(v.x, wr[4 * q + 0], a);
            a = fmaf(v.y, wr[4 * q + 1], a);
            a = fmaf(v.z, wr[4 * q + 2], a);
            a = fmaf(v.w, wr[4 * q + 3], a);
        }
        if (valid) out[hb + (size_t)(gbase + gg) * ncol + colc] = a;
    }
}

// ----------------------------------------------------------------
extern "C" void kernel_launch(void* const* d_in, const int* in_sizes, int n_in,
                              void* d_out, int out_size, void* d_ws, size_t ws_size,
                              hipStream_t stream) {
    const float* x     = (const float*)d_in[0];
    const int*   ei    = (const int*)d_in[1];
    const float* ew    = (const float*)d_in[2];
    const int*   batch = (const int*)d_in[4];
    const float* Win   = (const float*)d_in[6];
    const float* Wmsg  = (const float*)d_in[7];
    const float* W1    = (const float*)d_in[8];
    const float* W2    = (const float*)d_in[9];
    const float* Wa    = (const float*)d_in[10];
    const float* Ws    = (const float*)d_in[11];
    const float* Wt    = (const float*)d_in[12];
    const float* Wact  = (const float*)d_in[13];
    const float* Wv1   = (const float*)d_in[14];
    const float* Wv2   = (const float*)d_in[15];
    float* out = (float*)d_out;

    char* p = (char*)d_ws;
    const size_t nb = (size_t)NODES * HDIM * 2;                  // 32 MB
    unsigned char*  h0f8   = (unsigned char*)p;   p += (size_t)NODES * HDIM;   // 16 MB
    unsigned short* msgb   = (unsigned short*)p;  p += nb;
    float*          gsum   = (float*)p;           p += (size_t)NGRAPH * HDIM * 4;
    float*          s2g    = (float*)p;           p += (size_t)NGRAPH * 64 * 4;
    unsigned short* wfrag  = (unsigned short*)p;  p += 32 * 64 * 16;
    unsigned short* winfrag= (unsigned short*)p;  p += 8 * 64 * 16;
    int*            cnt    = (int*)p;             p += (size_t)NGRAPH * 4;
    int*            ccur   = (int*)p;             p += NB * 4;
    uint2*          scratch= (uint2*)p;           p += (size_t)NB * MAXPER * 8;   // 10.5 MB
    int2*           nbe    = (int2*)p;            p += (size_t)NODES * 8;
    int2*           csre   = (int2*)p;            p += (size_t)EDGES * 8;

    kprep        <<<15, 256, 0, stream>>>(Wmsg, Win, wfrag, winfrag, batch, cnt, gsum, ccur);
    k1_fused     <<<NB + 1024, 256, 0, stream>>>(x, winfrag, h0f8, ei, ew, ccur, scratch);
    kp2_fine     <<<NB, 256, 0, stream>>>(scratch, ccur, nbe, csre);

    kg_gather    <<<NODES / 16, 256, 0, stream>>>(h0f8, nbe, csre, msgb, NODES);

    k3a_mfma_pool<<<NODES / 128, 256, 0, stream>>>(msgb, h0f8, wfrag, batch, gsum);

    k4a_backbone <<<NGRAPH, 128, 0, stream>>>(gsum, cnt, W1, W2, Wv1, Wv2, s2g, out);
    k4b_logits   <<<256, 256, 0, stream>>>(s2g, Wa, Ws, Wt, Wact, out);
}